// Round 4
// baseline (235.306 us; speedup 1.0000x reference)
//
#include <hip/hip_runtime.h>
#include <math.h>

#define Bq 8
#define Nq 325
#define F_INq 32
#define Tq 24
#define HCq 128
#define RX 136               // 128 Wh rows + 4 f1 rows + 4 f2 rows
#define ROWSTR (RX * Tq)     // 3264 floats per (b,n)
#define KMAX 4

// ---------------- prep: neighbor lists (blocks 0..324) + W-pack + xs zero (block 325)
__global__ __launch_bounds__(64) void prep_kernel(
    const float* __restrict__ iw, const float* __restrict__ ib,
    const float* __restrict__ adj, const float* __restrict__ Ww,
    const float* __restrict__ Wb, const float* __restrict__ attnw,
    int* __restrict__ nbr_cnt, int* __restrict__ nbr_idx, float* __restrict__ nbr_w,
    float* __restrict__ Wx, float* __restrict__ bx, float* __restrict__ xs) {
  int blk = blockIdx.x;
  int lane = threadIdx.x;
  if (blk == Nq) {
    // Wx[r][f], r<128: Ww rows; 128..131: a1-projected rows; 132..135: a2
    for (int o = lane; o < RX * F_INq; o += 64) {
      int r = o >> 5, f = o & 31;
      float v;
      if (r < HCq) {
        v = Ww[o];
      } else {
        int h = (r - HCq) & 3;
        int c0 = (r < 132) ? 0 : 32;
        v = 0.f;
        for (int c = 0; c < 32; ++c)
          v += Ww[(h * 32 + c) * F_INq + f] * attnw[h * 64 + c0 + c];
      }
      Wx[o] = v;
    }
    for (int r = lane; r < RX; r += 64) {
      float v;
      if (r < HCq) {
        v = Wb[r];
      } else {
        int h = (r - HCq) & 3;
        int c0 = (r < 132) ? 0 : 32;
        v = 0.f;
        for (int c = 0; c < 32; ++c) v += Wb[h * 32 + c] * attnw[h * 64 + c0 + c];
      }
      bx[r] = v;
    }
    for (int e = lane; e < Bq * F_INq * Tq; e += 64) xs[e] = 0.f;
    return;
  }
  // neighbor extraction for row i
  __shared__ float wrow[Nq];
  __shared__ float arow[Nq];
  int i = blk;
  const float* iwr = iw + (size_t)i * Nq;
  const float* ibr = ib + (size_t)i * Nq;
  const float* ar  = adj + (size_t)i * Nq;
  float sum = 0.f;
  for (int j = lane; j < Nq; j += 64) {
    float basev = ibr[j];
    float w = iwr[j];
    w = fminf(fmaxf(w, basev * 0.5f), basev * 1.5f);
    w = fmaxf(w, 0.f);
    float a = ar[j];
    float wa = w * a;
    wrow[j] = wa;
    arow[j] = a;
    sum += wa;
  }
  #pragma unroll
  for (int off = 32; off >= 1; off >>= 1) sum += __shfl_xor(sum, off, 64);
  if (sum == 0.f) sum = 1e-6f;
  float inv = 1.f / sum;
  __syncthreads();
  if (lane == 0) {
    #pragma unroll
    for (int k = 0; k < KMAX; ++k) { nbr_idx[i * KMAX + k] = 0; nbr_w[i * KMAX + k] = 0.f; }
    int cnt = 0;
    for (int j = 0; j < Nq; ++j) {
      if (arow[j] != 0.f) {
        if (cnt < KMAX) {
          nbr_idx[i * KMAX + cnt] = j;
          nbr_w[i * KMAX + cnt]   = wrow[j] * inv;
        }
        cnt++;
      }
    }
    nbr_cnt[i] = cnt < KMAX ? cnt : KMAX;
  }
}

// ---------------- wh v3: WhX[bn][r][t]; thread = (node g, row-half, t-column) -------
// W read via wave-uniform (scalar) loads; x staged via coalesced float4; xs atomics.
__global__ __launch_bounds__(192) void wh_kernel(
    const float* __restrict__ x, const float* __restrict__ Wx,
    const float* __restrict__ bx, float* __restrict__ WhX, float* __restrict__ xs) {
  __shared__ __align__(16) float sx[4 * 768];   // 12 KB: x for 4 nodes
  int tid = threadIdx.x;
  int BN0 = blockIdx.x * 4;
  const float4* x4 = (const float4*)x + (size_t)BN0 * 192;
  float4* s4 = (float4*)sx;
  #pragma unroll
  for (int j = 0; j < 4; ++j) {
    int idx = tid + j * 192;
    float4 v = x4[idx];
    s4[idx] = v;
    int g = idx / 192, rem = idx - g * 192;
    int b = (BN0 + g) / Nq;
    int f = rem / 6, t0 = (rem - f * 6) * 4;
    float* xp = xs + b * 768 + f * 24 + t0;
    atomicAdd(xp + 0, v.x); atomicAdd(xp + 1, v.y);
    atomicAdd(xp + 2, v.z); atomicAdd(xp + 3, v.w);
  }
  __syncthreads();
  int g = tid / 48;
  int rh = (tid / 24) & 1;
  int t = tid % 24;
  int r0 = rh * 68;
  const float* xl = sx + g * 768 + t;
  float xv[32];
  #pragma unroll
  for (int f = 0; f < 32; ++f) xv[f] = xl[f * 24];
  float* outp = WhX + (size_t)(BN0 + g) * ROWSTR + r0 * Tq + t;
  #pragma unroll 2
  for (int r = r0; r < r0 + 68; ++r) {
    const float* wr = Wx + r * 32;       // wave-uniform -> s_load
    float a0 = bx[r], a1 = 0.f, a2 = 0.f, a3 = 0.f;
    #pragma unroll
    for (int f = 0; f < 32; f += 4) {
      a0 += wr[f]     * xv[f];
      a1 += wr[f + 1] * xv[f + 1];
      a2 += wr[f + 2] * xv[f + 2];
      a3 += wr[f + 3] * xv[f + 3];
    }
    *outp = (a0 + a1) + (a2 + a3);
    outp += Tq;
  }
}

// ---------------- S[b][r][t] = sum_f Wx[r][f]*xs[b][f][t] + 325*bx[r], r<128 -------
__global__ __launch_bounds__(192) void sgemm_kernel(
    const float* __restrict__ xs, const float* __restrict__ Wx,
    const float* __restrict__ bx, float* __restrict__ S) {
  __shared__ __align__(16) float sxl[768];
  int b = blockIdx.x, tid = threadIdx.x;
  ((float4*)sxl)[tid] = ((const float4*)(xs + b * 768))[tid];
  __syncthreads();
  int rg = tid / 24, t = tid % 24;
  float xv[32];
  #pragma unroll
  for (int f = 0; f < 32; ++f) xv[f] = sxl[f * 24 + t];
  float* op = S + b * (HCq * Tq) + rg * 16 * Tq + t;
  #pragma unroll 2
  for (int r = rg * 16; r < rg * 16 + 16; ++r) {
    const float* wr = Wx + r * 32;
    float a0 = 325.f * bx[r], a1 = 0.f, a2 = 0.f, a3 = 0.f;
    #pragma unroll
    for (int f = 0; f < 32; f += 4) {
      a0 += wr[f]     * xv[f];
      a1 += wr[f + 1] * xv[f + 1];
      a2 += wr[f + 2] * xv[f + 2];
      a3 += wr[f + 3] * xv[f + 3];
    }
    *op = (a0 + a1) + (a2 + a3);
    op += Tq;
  }
}

// ---------------- sparse softmax attention, float4-linear phase 2 ----------------
__global__ __launch_bounds__(256) void attn_kernel(
    const float* __restrict__ WhX, const float* __restrict__ S,
    const int* __restrict__ nbr_cnt, const int* __restrict__ nbr_idx,
    const float* __restrict__ nbr_w, float* __restrict__ out) {
  __shared__ __align__(16) float sF1[96];     // f1 rows of node i   (rows 128..131)
  __shared__ __align__(16) float sFj[3][96];  // f2 rows of neighbors (rows 132..135)
  __shared__ __align__(16) float sbp[96];     // basep[h][t]
  __shared__ __align__(16) float spd[3][96];  // (p_k/Z - basep)[h][t]
  __shared__ int sidx[KMAX];
  __shared__ float sw[KMAX];
  __shared__ int scnt;
  int bi = blockIdx.x;
  int b = bi / Nq, i = bi - b * Nq;
  int tid = threadIdx.x;
  if (tid == 0) { int c = nbr_cnt[i]; scnt = c < 3 ? c : 3; }
  if (tid < KMAX) { sidx[tid] = nbr_idx[i * KMAX + tid]; sw[tid] = nbr_w[i * KMAX + tid]; }
  __syncthreads();
  int cnt = scnt;
  const float* wb = WhX + (size_t)b * Nq * ROWSTR;
  if (tid < 96) sF1[tid] = wb[(size_t)i * ROWSTR + HCq * Tq + tid];
  for (int idx = tid; idx < 288; idx += 256) {
    int k = idx / 96, r = idx - k * 96;
    sFj[k][r] = wb[(size_t)sidx[k] * ROWSTR + 132 * Tq + r];
  }
  __syncthreads();
  if (tid < 96) {
    float f1v = sF1[tid];
    float sv[3];
    float m = 0.f;                      // >= N-cnt exact-zero scores exist
    #pragma unroll
    for (int k = 0; k < 3; ++k) {
      float s = 0.f;
      if (k < cnt) {
        float e = f1v + sFj[k][tid];
        e = e > 0.f ? e : 0.2f * e;     // leaky_relu 0.2
        s = e + sw[k];
        m = fmaxf(m, s);
      }
      sv[k] = s;
    }
    float em = __expf(-m);
    float Z = (float)(Nq - cnt) * em;
    float pk[3];
    #pragma unroll
    for (int k = 0; k < 3; ++k) {
      float p = 0.f;
      if (k < cnt) { p = __expf(sv[k] - m); Z += p; }
      pk[k] = p;
    }
    float invZ = 1.f / Z;
    float bp = em * invZ;
    sbp[tid] = bp;
    #pragma unroll
    for (int k = 0; k < 3; ++k) spd[k][tid] = (k < cnt) ? pk[k] * invZ - bp : 0.f;
  }
  __syncthreads();
  // phase 2: 768 output float4s per (b,i); thread owns e = tid, tid+256, tid+512
  const float4* sp4 = (const float4*)(S + b * (HCq * Tq));
  const float4* w04 = (const float4*)(wb + (size_t)sidx[0] * ROWSTR);
  const float4* w14 = (const float4*)(wb + (size_t)sidx[1] * ROWSTR);
  const float4* w24 = (const float4*)(wb + (size_t)sidx[2] * ROWSTR);
  float4* op4 = (float4*)(out + (size_t)bi * (HCq * Tq));
  #pragma unroll
  for (int j = 0; j < 3; ++j) {
    int e = tid + j * 256;              // float4 index in [0,768)
    int co = 4 * e;                     // flat float offset in [0,3072)
    int h = e / 192;                    // = (co/24) >> 5
    int t0 = co % 24;                   // multiple of 4, never crosses a t-row
    int so = h * 24 + t0;
    float4 bp4 = *(const float4*)(sbp + so);
    float4 p0  = *(const float4*)(&spd[0][so]);
    float4 p1  = *(const float4*)(&spd[1][so]);
    float4 p2  = *(const float4*)(&spd[2][so]);
    float4 s4  = sp4[e];
    float4 w0  = w04[e];
    float4 w1  = w14[e];
    float4 w2  = w24[e];
    float4 o;
    o.x = bp4.x * s4.x + p0.x * w0.x + p1.x * w1.x + p2.x * w2.x;
    o.y = bp4.y * s4.y + p0.y * w0.y + p1.y * w1.y + p2.y * w2.y;
    o.z = bp4.z * s4.z + p0.z * w0.z + p1.z * w1.z + p2.z * w2.z;
    o.w = bp4.w * s4.w + p0.w * w0.w + p1.w * w1.w + p2.w * w2.w;
    op4[e] = o;
  }
}

extern "C" void kernel_launch(void* const* d_in, const int* in_sizes, int n_in,
                              void* d_out, int out_size, void* d_ws, size_t ws_size,
                              hipStream_t stream) {
  const float* x     = (const float*)d_in[0];
  const float* Ww    = (const float*)d_in[1];
  const float* Wb    = (const float*)d_in[2];
  const float* attnw = (const float*)d_in[3];
  const float* iw    = (const float*)d_in[4];
  const float* ib    = (const float*)d_in[5];
  const float* adj   = (const float*)d_in[6];
  float* out = (float*)d_out;

  float* ws = (float*)d_ws;
  const size_t WHX_SZ = (size_t)Bq * Nq * ROWSTR;   // 8,486,400
  const size_t S_SZ   = (size_t)Bq * HCq * Tq;      // 24,576
  float* WhX = ws;
  float* S   = WhX + WHX_SZ;
  float* Wx  = S + S_SZ;
  float* bx  = Wx + RX * F_INq;
  float* xs  = bx + RX;
  int* nbr_cnt = (int*)(xs + Bq * F_INq * Tq);
  int* nbr_idx = nbr_cnt + Nq;
  float* nbr_w = (float*)(nbr_idx + Nq * KMAX);

  prep_kernel<<<Nq + 1, 64, 0, stream>>>(iw, ib, adj, Ww, Wb, attnw,
                                         nbr_cnt, nbr_idx, nbr_w, Wx, bx, xs);
  wh_kernel<<<(Bq * Nq) / 4, 192, 0, stream>>>(x, Wx, bx, WhX, xs);
  sgemm_kernel<<<Bq, 192, 0, stream>>>(xs, Wx, bx, S);
  attn_kernel<<<Bq * Nq, 256, 0, stream>>>(WhX, S, nbr_cnt, nbr_idx, nbr_w, out);
}

// Round 5
// 130.866 us; speedup vs baseline: 1.7981x; 1.7981x over previous
//
#include <hip/hip_runtime.h>
#include <math.h>

#define Bq 8
#define Nq 325
#define F_INq 32
#define Tq 24
#define HCq 128
#define KMAX 4

// ---------------- prep: neighbor lists (blocks 0..324) + weight packs (block 325) ---
__global__ __launch_bounds__(64) void prep_kernel(
    const float* __restrict__ iw, const float* __restrict__ ib,
    const float* __restrict__ adj, const float* __restrict__ Ww,
    const float* __restrict__ Wb, const float* __restrict__ attnw,
    int* __restrict__ nbr_cnt, int* __restrict__ nbr_idx, float* __restrict__ nbr_w,
    float* __restrict__ Wx, float* __restrict__ WxT, float* __restrict__ Wp,
    float* __restrict__ bx) {
  int blk = blockIdx.x;
  int lane = threadIdx.x;
  if (blk == Nq) {
    // Wx[r][f] = Ww (rows 0..127), for sgemm
    for (int o = lane; o < HCq * F_INq; o += 64) Wx[o] = Ww[o];
    // WxT[f][r] = Ww[r][f], for fused GEMM scalar loads
    for (int o = lane; o < F_INq * HCq; o += 64) {
      int f = o >> 7, r = o & 127;
      WxT[o] = Ww[r * F_INq + f];
    }
    // Wp[p][f]: p=0..3 a1-projected row for head p; p=4..7 a2-projected
    for (int o = lane; o < 8 * F_INq; o += 64) {
      int p = o >> 5, f = o & 31;
      int h = p & 3, c0 = (p < 4) ? 0 : 32;
      float v = 0.f;
      for (int c = 0; c < 32; ++c)
        v += Ww[(h * 32 + c) * F_INq + f] * attnw[h * 64 + c0 + c];
      Wp[o] = v;
    }
    // bx[0..127] = Wb; bx[128+h] = a1-proj bias; bx[132+h] = a2-proj bias
    for (int r = lane; r < 136; r += 64) {
      float v;
      if (r < HCq) {
        v = Wb[r];
      } else {
        int h = (r - HCq) & 3, c0 = (r < 132) ? 0 : 32;
        v = 0.f;
        for (int c = 0; c < 32; ++c) v += Wb[h * 32 + c] * attnw[h * 64 + c0 + c];
      }
      bx[r] = v;
    }
    return;
  }
  // neighbor extraction for row i
  __shared__ float wrow[Nq];
  __shared__ float arow[Nq];
  int i = blk;
  const float* iwr = iw + (size_t)i * Nq;
  const float* ibr = ib + (size_t)i * Nq;
  const float* ar  = adj + (size_t)i * Nq;
  float sum = 0.f;
  for (int j = lane; j < Nq; j += 64) {
    float basev = ibr[j];
    float w = iwr[j];
    w = fminf(fmaxf(w, basev * 0.5f), basev * 1.5f);
    w = fmaxf(w, 0.f);
    float a = ar[j];
    float wa = w * a;
    wrow[j] = wa;
    arow[j] = a;
    sum += wa;
  }
  #pragma unroll
  for (int off = 32; off >= 1; off >>= 1) sum += __shfl_xor(sum, off, 64);
  if (sum == 0.f) sum = 1e-6f;
  float inv = 1.f / sum;
  __syncthreads();
  if (lane == 0) {
    #pragma unroll
    for (int k = 0; k < KMAX; ++k) { nbr_idx[i * KMAX + k] = 0; nbr_w[i * KMAX + k] = 0.f; }
    int cnt = 0;
    for (int j = 0; j < Nq; ++j) {
      if (arow[j] != 0.f) {
        if (cnt < KMAX) {
          nbr_idx[i * KMAX + cnt] = j;
          nbr_w[i * KMAX + cnt]   = wrow[j] * inv;
        }
        cnt++;
      }
    }
    nbr_cnt[i] = cnt < KMAX ? cnt : KMAX;
  }
}

// ---------------- xpart: partial sums of x over n (no atomics) ----------------------
__global__ __launch_bounds__(192) void xpart_kernel(
    const float* __restrict__ x, float* __restrict__ xp) {
  int blk = blockIdx.x;                 // b*13 + c
  int b = blk / 13, c = blk - b * 13;
  int tid = threadIdx.x;
  const float4* src = (const float4*)x + ((size_t)b * Nq + c * 25) * 192;
  float4 a = {0.f, 0.f, 0.f, 0.f};
  #pragma unroll 5
  for (int n = 0; n < 25; ++n) {
    float4 v = src[(size_t)n * 192 + tid];
    a.x += v.x; a.y += v.y; a.z += v.z; a.w += v.w;
  }
  ((float4*)xp)[(size_t)blk * 192 + tid] = a;
}

// ---------------- sgemm: S[b][r][t] = 325*bx[r] + sum_f Wx[r][f]*xs[b][f][t] --------
__global__ __launch_bounds__(192) void sgemm_kernel(
    const float* __restrict__ xp, const float* __restrict__ Wx,
    const float* __restrict__ bx, float* __restrict__ S) {
  __shared__ __align__(16) float sxl[768];
  int b = blockIdx.x, tid = threadIdx.x;
  float4 a = {0.f, 0.f, 0.f, 0.f};
  #pragma unroll
  for (int c = 0; c < 13; ++c) {
    float4 v = ((const float4*)xp)[(size_t)(b * 13 + c) * 192 + tid];
    a.x += v.x; a.y += v.y; a.z += v.z; a.w += v.w;
  }
  ((float4*)sxl)[tid] = a;
  __syncthreads();
  int rg = tid / 24, t = tid % 24;
  float xv[32];
  #pragma unroll
  for (int f = 0; f < 32; ++f) xv[f] = sxl[f * 24 + t];
  float* op = S + b * (HCq * Tq) + rg * 16 * Tq + t;
  #pragma unroll 2
  for (int r = rg * 16; r < rg * 16 + 16; ++r) {
    const float* wr = Wx + r * 32;
    float a0 = 325.f * bx[r], a1 = 0.f, a2 = 0.f, a3 = 0.f;
    #pragma unroll
    for (int f = 0; f < 32; f += 4) {
      a0 += wr[f]     * xv[f];
      a1 += wr[f + 1] * xv[f + 1];
      a2 += wr[f + 2] * xv[f + 2];
      a3 += wr[f + 3] * xv[f + 3];
    }
    *op = (a0 + a1) + (a2 + a3);
    op += Tq;
  }
}

// ---------------- fused: tables + y-build + GEMM + coalesced store ------------------
// Block handles 2 consecutive (b,i). Wave w <-> head h=w, rows 32w..32w+31.
__global__ __launch_bounds__(256) void fused_kernel(
    const float* __restrict__ x, const float* __restrict__ Wp,
    const float* __restrict__ WxT, const float* __restrict__ bx,
    const float* __restrict__ S,
    const int* __restrict__ nbr_cnt, const int* __restrict__ nbr_idx,
    const float* __restrict__ nbr_w, float* __restrict__ out) {
  __shared__ __align__(16) float sx[2 * 4 * 768];    // [ii][slot][f*24+t]; slot0=self,1..3=nbrs
  __shared__ __align__(16) float yot[2 * 3072];      // y: [ii][h*768+f*24+t]; later ot: [ii][r*24+t]
  __shared__ __align__(16) float spd[2][3][96];      // pd_k[ii][k][h*24+t]
  __shared__ float sbp[2][96], sps[2][96];
  __shared__ float ssw[2][3];
  __shared__ int ssi[2][3], scnt2[2];
  int tid = threadIdx.x;
  int blk = blockIdx.x;
  int bi0 = blk * 2;
  if (tid < 2) {
    int i = (bi0 + tid) % Nq;
    int c = nbr_cnt[i];
    scnt2[tid] = c < 3 ? c : 3;
  }
  if (tid < 6) {
    int ii = tid / 3, k = tid - ii * 3;
    int i = (bi0 + ii) % Nq;
    ssi[ii][k] = nbr_idx[i * KMAX + k];
    ssw[ii][k] = nbr_w[i * KMAX + k];
  }
  __syncthreads();
  // ---- stage x for 8 node-slots, fully coalesced float4 ----
  const float4* x4 = (const float4*)x;
  float4* sx4 = (float4*)sx;
  #pragma unroll
  for (int j = 0; j < 6; ++j) {
    int idx = tid + j * 256;            // [0,1536)
    int slot = idx / 192, e4 = idx - slot * 192;
    int ii = slot >> 2, sl = slot & 3;
    int b = (bi0 + ii) / Nq;
    int node = (sl == 0) ? ((bi0 + ii) % Nq) : ssi[ii][sl - 1];
    sx4[idx] = x4[((size_t)(b * Nq + node)) * 192 + e4];
  }
  __syncthreads();
  // ---- tables: f1(self) + f2(3 nbrs) -> sparse softmax factors ----
  if (tid < 192) {
    int ii = tid / 96, r96 = tid - ii * 96;
    int h = r96 / 24, t = r96 - h * 24;
    const float* xi = sx + (ii * 4 + 0) * 768 + t;
    const float* xj0 = sx + (ii * 4 + 1) * 768 + t;
    const float* xj1 = sx + (ii * 4 + 2) * 768 + t;
    const float* xj2 = sx + (ii * 4 + 3) * 768 + t;
    const float* w1 = Wp + h * 32;
    const float* w2 = Wp + (4 + h) * 32;
    float f1 = bx[128 + h], g0 = bx[132 + h], g1 = g0, g2 = g0;
    #pragma unroll
    for (int f = 0; f < 32; ++f) {
      float wa = w1[f], wb2 = w2[f];
      f1 += wa * xi[f * 24];
      g0 += wb2 * xj0[f * 24];
      g1 += wb2 * xj1[f * 24];
      g2 += wb2 * xj2[f * 24];
    }
    int cnt = scnt2[ii];
    float fv[3] = {g0, g1, g2};
    float sv[3];
    float m = 0.f;                       // >= N-cnt exact-zero score entries
    #pragma unroll
    for (int k = 0; k < 3; ++k) {
      float s = 0.f;
      if (k < cnt) {
        float e = f1 + fv[k];
        e = e > 0.f ? e : 0.2f * e;      // leaky_relu 0.2
        s = e + ssw[ii][k];
        m = fmaxf(m, s);
      }
      sv[k] = s;
    }
    float em = __expf(-m);
    float Z = (float)(Nq - cnt) * em;
    float pk[3];
    #pragma unroll
    for (int k = 0; k < 3; ++k) {
      float p = 0.f;
      if (k < cnt) { p = __expf(sv[k] - m); Z += p; }
      pk[k] = p;
    }
    float invZ = 1.f / Z;
    float bp = em * invZ;
    float ps = 0.f;
    sbp[ii][r96] = bp;
    #pragma unroll
    for (int k = 0; k < 3; ++k) {
      float pd = (k < cnt) ? pk[k] * invZ - bp : 0.f;
      spd[ii][k][r96] = pd;
      ps += pd;
    }
    sps[ii][r96] = ps;
  }
  __syncthreads();
  // ---- y[ii][h][f][t] = sum_k pd_k[ii][h][t] * x_jk[ii][f][t] (float4 over t) ----
  float4* y4 = (float4*)yot;
  #pragma unroll
  for (int j = 0; j < 6; ++j) {
    int idx = tid + j * 256;             // [0,1536)
    int ii = idx / 768, rem = idx - ii * 768;
    int h = rem / 192, fe4 = rem - h * 192;
    int fe = fe4 * 4;
    int t0 = fe % 24;
    int co = h * 24 + t0;
    float4 p0 = *(const float4*)(&spd[ii][0][co]);
    float4 p1 = *(const float4*)(&spd[ii][1][co]);
    float4 p2 = *(const float4*)(&spd[ii][2][co]);
    float4 xa = sx4[(ii * 4 + 1) * 192 + fe4];
    float4 xb = sx4[(ii * 4 + 2) * 192 + fe4];
    float4 xc = sx4[(ii * 4 + 3) * 192 + fe4];
    float4 y;
    y.x = p0.x * xa.x + p1.x * xb.x + p2.x * xc.x;
    y.y = p0.y * xa.y + p1.y * xb.y + p2.y * xc.y;
    y.z = p0.z * xa.z + p1.z * xb.z + p2.z * xc.z;
    y.w = p0.w * xa.w + p1.w * xb.w + p2.w * xc.w;
    y4[idx] = y;
  }
  __syncthreads();
  // ---- GEMM: out[r][t] = bp*S[r][t] + ps*bx[r] + sum_f WxT[f][r]*y[h][f][t] ----
  int lane = tid & 63;
  int w = __builtin_amdgcn_readfirstlane(tid >> 6);   // wave id = head h (uniform)
  float acc[32];
  int ii = lane / 24, t = lane - ii * 24;
  bool act = (lane < 48);
  if (act) {
    int b = (bi0 + ii) / Nq;
    float bpv = sbp[ii][w * 24 + t];
    float psv = sps[ii][w * 24 + t];
    const float* Sp = S + b * 3072 + (w * 32) * 24 + t;
    const float* bxp = bx + w * 32;                   // uniform -> s_load
    #pragma unroll
    for (int r = 0; r < 32; ++r) acc[r] = bpv * Sp[r * 24] + psv * bxp[r];
    const float* yp = yot + ii * 3072 + w * 768 + t;
    const float* wtp = WxT + w * 32;                  // uniform -> s_load
    #pragma unroll 4
    for (int f = 0; f < 32; ++f) {
      float yv = yp[f * 24];
      const float* wr = wtp + f * 128;
      #pragma unroll
      for (int r = 0; r < 32; ++r) acc[r] += wr[r] * yv;
    }
  }
  __syncthreads();                       // all waves done reading y before ot overwrite
  if (act) {
    float* otp = yot + ii * 3072 + (w * 32) * 24 + t;
    #pragma unroll
    for (int r = 0; r < 32; ++r) otp[r * 24] = acc[r];
  }
  __syncthreads();
  // ---- coalesced float4 store of both nodes' 12 KB ----
  float4* o4 = (float4*)(out + (size_t)bi0 * 3072);
  #pragma unroll
  for (int j = 0; j < 6; ++j) {
    int idx = tid + j * 256;
    o4[idx] = y4[idx];
  }
}

extern "C" void kernel_launch(void* const* d_in, const int* in_sizes, int n_in,
                              void* d_out, int out_size, void* d_ws, size_t ws_size,
                              hipStream_t stream) {
  const float* x     = (const float*)d_in[0];
  const float* Ww    = (const float*)d_in[1];
  const float* Wb    = (const float*)d_in[2];
  const float* attnw = (const float*)d_in[3];
  const float* iw    = (const float*)d_in[4];
  const float* ib    = (const float*)d_in[5];
  const float* adj   = (const float*)d_in[6];
  float* out = (float*)d_out;

  float* ws = (float*)d_ws;
  float* xp  = ws;                        // 8*13*768 = 79,872
  float* S   = xp + (size_t)Bq * 13 * 768;// 24,576
  float* Wx  = S + (size_t)Bq * HCq * Tq; // 4,096
  float* WxT = Wx + HCq * F_INq;          // 4,096
  float* Wp  = WxT + F_INq * HCq;         // 256
  float* bx  = Wp + 8 * F_INq;            // 136
  int* nbr_cnt = (int*)(bx + 136);
  int* nbr_idx = nbr_cnt + Nq;
  float* nbr_w = (float*)(nbr_idx + Nq * KMAX);

  prep_kernel<<<Nq + 1, 64, 0, stream>>>(iw, ib, adj, Ww, Wb, attnw,
                                         nbr_cnt, nbr_idx, nbr_w, Wx, WxT, Wp, bx);
  xpart_kernel<<<Bq * 13, 192, 0, stream>>>(x, xp);
  sgemm_kernel<<<Bq, 192, 0, stream>>>(xp, Wx, bx, S);
  fused_kernel<<<(Bq * Nq) / 2, 256, 0, stream>>>(x, Wp, WxT, bx, S,
                                                  nbr_cnt, nbr_idx, nbr_w, out);
}

// Round 6
// 112.864 us; speedup vs baseline: 2.0849x; 1.1595x over previous
//
#include <hip/hip_runtime.h>
#include <math.h>

#define Bq 8
#define Nq 325
#define F_INq 32
#define Tq 24
#define HCq 128
#define KMAX 4

// ---- K1: blocks 0..324 neighbor extract (wave0 only, register-resident, ballot) ----
//      block 325: weight packs; blocks 326..429: xpart partial sums
__global__ __launch_bounds__(192) void prep_kernel(
    const float* __restrict__ iw, const float* __restrict__ ib,
    const float* __restrict__ adj, const float* __restrict__ Ww,
    const float* __restrict__ Wb, const float* __restrict__ attnw,
    const float* __restrict__ x,
    int* __restrict__ nbr_cnt, int* __restrict__ nbr_idx, float* __restrict__ nbr_w,
    float* __restrict__ Wx, float* __restrict__ WxT, float* __restrict__ Wp,
    float* __restrict__ bx, float* __restrict__ xp) {
  int blk = blockIdx.x;
  int tid = threadIdx.x;
  if (blk < Nq) {
    if (tid >= 64) return;               // wave 0 only; no barriers in this path
    int lane = tid;
    int i = blk;
    const float* iwr = iw + (size_t)i * Nq;
    const float* ibr = ib + (size_t)i * Nq;
    const float* ar  = adj + (size_t)i * Nq;
    float wa_c[6], a_c[6];
    float sum = 0.f;
    #pragma unroll
    for (int c = 0; c < 6; ++c) {
      int j = c * 64 + lane;
      float wa = 0.f, a = 0.f;
      if (j < Nq) {
        float basev = ibr[j];
        float w = iwr[j];
        w = fminf(fmaxf(w, basev * 0.5f), basev * 1.5f);
        w = fmaxf(w, 0.f);
        a = ar[j];
        wa = w * a;
      }
      wa_c[c] = wa; a_c[c] = a;
      sum += wa;
    }
    #pragma unroll
    for (int off = 32; off >= 1; off >>= 1) sum += __shfl_xor(sum, off, 64);
    if (sum == 0.f) sum = 1e-6f;
    float inv = 1.f / sum;
    unsigned long long below = (1ull << lane) - 1ull;
    int base = 0;
    #pragma unroll
    for (int c = 0; c < 6; ++c) {
      int j = c * 64 + lane;
      bool pred = (j < Nq) && (a_c[c] != 0.f);
      unsigned long long m = __ballot(pred);
      int rank = base + __popcll(m & below);
      if (pred && rank < KMAX) {
        nbr_idx[i * KMAX + rank] = j;
        nbr_w[i * KMAX + rank]   = wa_c[c] * inv;
      }
      base += __popcll(m);
    }
    if (lane == 0) {
      // pad unused slots deterministically
      int cnt = base < KMAX ? base : KMAX;
      for (int k = cnt; k < KMAX; ++k) { nbr_idx[i * KMAX + k] = 0; nbr_w[i * KMAX + k] = 0.f; }
      nbr_cnt[i] = cnt;
    }
    return;
  }
  if (blk == Nq) {
    for (int o = tid; o < HCq * F_INq; o += 192) Wx[o] = Ww[o];
    for (int o = tid; o < F_INq * HCq; o += 192) {
      int f = o >> 7, r = o & 127;
      WxT[o] = Ww[r * F_INq + f];
    }
    for (int o = tid; o < 8 * F_INq; o += 192) {
      int p = o >> 5, f = o & 31;
      int h = p & 3, c0 = (p < 4) ? 0 : 32;
      float v = 0.f;
      for (int c = 0; c < 32; ++c)
        v += Ww[(h * 32 + c) * F_INq + f] * attnw[h * 64 + c0 + c];
      Wp[o] = v;
    }
    for (int r = tid; r < 136; r += 192) {
      float v;
      if (r < HCq) {
        v = Wb[r];
      } else {
        int h = (r - HCq) & 3, c0 = (r < 132) ? 0 : 32;
        v = 0.f;
        for (int c = 0; c < 32; ++c) v += Wb[h * 32 + c] * attnw[h * 64 + c0 + c];
      }
      bx[r] = v;
    }
    return;
  }
  // xpart: partial sums of x over 25-node chunks
  {
    int pblk = blk - (Nq + 1);            // 0..103
    int b = pblk / 13, c = pblk - b * 13;
    const float4* src = (const float4*)x + ((size_t)b * Nq + c * 25) * 192;
    float4 a = {0.f, 0.f, 0.f, 0.f};
    #pragma unroll 5
    for (int n = 0; n < 25; ++n) {
      float4 v = src[(size_t)n * 192 + tid];
      a.x += v.x; a.y += v.y; a.z += v.z; a.w += v.w;
    }
    ((float4*)xp)[(size_t)pblk * 192 + tid] = a;
  }
}

// ---- K2: S[b][r][t] = 325*bx[r] + sum_f Wx[r][f]*xs[b][f][t] ----------------------
__global__ __launch_bounds__(192) void sgemm_kernel(
    const float* __restrict__ xp, const float* __restrict__ Wx,
    const float* __restrict__ bx, float* __restrict__ S) {
  __shared__ __align__(16) float sxl[768];
  int b = blockIdx.x, tid = threadIdx.x;
  float4 a = {0.f, 0.f, 0.f, 0.f};
  #pragma unroll
  for (int c = 0; c < 13; ++c) {
    float4 v = ((const float4*)xp)[(size_t)(b * 13 + c) * 192 + tid];
    a.x += v.x; a.y += v.y; a.z += v.z; a.w += v.w;
  }
  ((float4*)sxl)[tid] = a;
  __syncthreads();
  int rg = tid / 24, t = tid % 24;
  float xv[32];
  #pragma unroll
  for (int f = 0; f < 32; ++f) xv[f] = sxl[f * 24 + t];
  float* op = S + b * (HCq * Tq) + rg * 16 * Tq + t;
  #pragma unroll 2
  for (int r = rg * 16; r < rg * 16 + 16; ++r) {
    const float* wr = Wx + r * 32;
    float a0 = 325.f * bx[r], a1 = 0.f, a2 = 0.f, a3 = 0.f;
    #pragma unroll
    for (int f = 0; f < 32; f += 4) {
      a0 += wr[f]     * xv[f];
      a1 += wr[f + 1] * xv[f + 1];
      a2 += wr[f + 2] * xv[f + 2];
      a3 += wr[f + 3] * xv[f + 3];
    }
    *op = (a0 + a1) + (a2 + a3);
    op += Tq;
  }
}

// ---- K3: fused tables + GEMM (y folded, register pd) + coalesced store ------------
// Block = 2 consecutive (b,i). Wave w <-> head h=w (rows 32w..32w+31).
__global__ __launch_bounds__(256) void fused_kernel(
    const float* __restrict__ x, const float* __restrict__ Wp,
    const float* __restrict__ WxT, const float* __restrict__ bx,
    const float* __restrict__ S,
    const int* __restrict__ nbr_cnt, const int* __restrict__ nbr_idx,
    const float* __restrict__ nbr_w, float* __restrict__ out) {
  __shared__ __align__(16) float sx[2 * 4 * 768];   // x tiles; later reused as out tile
  __shared__ __align__(16) float spd[2][3][96];     // pd_k[ii][k][h*24+t]
  __shared__ float sbp[2][96], sps[2][96];
  __shared__ float ssw[2][3];
  __shared__ int ssi[2][3], scnt2[2];
  int tid = threadIdx.x;
  int bi0 = blockIdx.x * 2;
  if (tid < 2) {
    int c = nbr_cnt[(bi0 + tid) % Nq];
    scnt2[tid] = c < 3 ? c : 3;
  }
  if (tid < 6) {
    int ii = tid / 3, k = tid - ii * 3;
    int i = (bi0 + ii) % Nq;
    ssi[ii][k] = nbr_idx[i * KMAX + k];
    ssw[ii][k] = nbr_w[i * KMAX + k];
  }
  __syncthreads();
  // stage x for 8 node-slots (self + 3 nbrs per node), coalesced float4
  const float4* x4 = (const float4*)x;
  float4* sx4 = (float4*)sx;
  #pragma unroll
  for (int j = 0; j < 6; ++j) {
    int idx = tid + j * 256;              // [0,1536)
    int slot = idx / 192, e4 = idx - slot * 192;
    int ii = slot >> 2, sl = slot & 3;
    int b = (bi0 + ii) / Nq;
    int node = (sl == 0) ? ((bi0 + ii) % Nq) : ssi[ii][sl - 1];
    sx4[idx] = x4[((size_t)(b * Nq + node)) * 192 + e4];
  }
  __syncthreads();
  // tables: f1(self)+f2(nbrs) -> sparse-softmax factors per (ii,h,t)
  if (tid < 192) {
    int ii = tid / 96, r96 = tid - ii * 96;
    int h = r96 / 24, t = r96 - h * 24;
    const float* xi  = sx + (ii * 4 + 0) * 768 + t;
    const float* xj0 = sx + (ii * 4 + 1) * 768 + t;
    const float* xj1 = sx + (ii * 4 + 2) * 768 + t;
    const float* xj2 = sx + (ii * 4 + 3) * 768 + t;
    const float* w1 = Wp + h * 32;
    const float* w2 = Wp + (4 + h) * 32;
    float f1 = bx[128 + h], g0 = bx[132 + h], g1 = g0, g2 = g0;
    #pragma unroll
    for (int f = 0; f < 32; ++f) {
      float wa = w1[f], wb2 = w2[f];
      f1 += wa * xi[f * 24];
      g0 += wb2 * xj0[f * 24];
      g1 += wb2 * xj1[f * 24];
      g2 += wb2 * xj2[f * 24];
    }
    int cnt = scnt2[ii];
    float fv[3] = {g0, g1, g2};
    float sv[3];
    float m = 0.f;                        // >= N-cnt exact-zero score entries
    #pragma unroll
    for (int k = 0; k < 3; ++k) {
      float s = 0.f;
      if (k < cnt) {
        float e = f1 + fv[k];
        e = e > 0.f ? e : 0.2f * e;       // leaky_relu 0.2
        s = e + ssw[ii][k];
        m = fmaxf(m, s);
      }
      sv[k] = s;
    }
    float em = __expf(-m);
    float Z = (float)(Nq - cnt) * em;
    float pk[3];
    #pragma unroll
    for (int k = 0; k < 3; ++k) {
      float p = 0.f;
      if (k < cnt) { p = __expf(sv[k] - m); Z += p; }
      pk[k] = p;
    }
    float invZ = 1.f / Z;
    float bp = em * invZ;
    float ps = 0.f;
    sbp[ii][r96] = bp;
    #pragma unroll
    for (int k = 0; k < 3; ++k) {
      float pd = (k < cnt) ? pk[k] * invZ - bp : 0.f;
      spd[ii][k][r96] = pd;
      ps += pd;
    }
    sps[ii][r96] = ps;
  }
  __syncthreads();
  // GEMM: acc[r] = bp*S[r][t] + ps*bx[r] + sum_f W[f][r]*(p0*x1+p1*x2+p2*x3)[f][t]
  int lane = tid & 63;
  int w = __builtin_amdgcn_readfirstlane(tid >> 6);   // wave id = head (uniform)
  int ii = lane / 24, t = lane - ii * 24;
  bool act = (lane < 48);
  float acc[32];
  if (act) {
    int b = (bi0 + ii) / Nq;
    int ht = w * 24 + t;
    float bpv = sbp[ii][ht];
    float psv = sps[ii][ht];
    float p0 = spd[ii][0][ht], p1 = spd[ii][1][ht], p2 = spd[ii][2][ht];
    const float* Sp  = S + b * 3072 + (w * 32) * 24 + t;
    const float* bxp = bx + w * 32;                   // uniform -> s_load
    #pragma unroll
    for (int r = 0; r < 32; ++r) acc[r] = bpv * Sp[r * 24] + psv * bxp[r];
    const float* xj0 = sx + (ii * 4 + 1) * 768 + t;
    const float* xj1 = sx + (ii * 4 + 2) * 768 + t;
    const float* xj2 = sx + (ii * 4 + 3) * 768 + t;
    const float* wtp = WxT + w * 32;                  // uniform -> s_load
    #pragma unroll 4
    for (int f = 0; f < 32; ++f) {
      float yv = p0 * xj0[f * 24] + p1 * xj1[f * 24] + p2 * xj2[f * 24];
      const float* wr = wtp + f * 128;
      #pragma unroll
      for (int r = 0; r < 32; ++r) acc[r] += wr[r] * yv;
    }
  }
  __syncthreads();                        // all reads of sx done before overwrite
  if (act) {
    float* otp = sx + ii * 3072 + (w * 32) * 24 + t;
    #pragma unroll
    for (int r = 0; r < 32; ++r) otp[r * 24] = acc[r];
  }
  __syncthreads();
  // coalesced float4 store of both nodes' 12 KB
  float4* o4 = (float4*)(out + (size_t)bi0 * 3072);
  #pragma unroll
  for (int j = 0; j < 6; ++j) {
    int idx = tid + j * 256;
    o4[idx] = sx4[idx];
  }
}

extern "C" void kernel_launch(void* const* d_in, const int* in_sizes, int n_in,
                              void* d_out, int out_size, void* d_ws, size_t ws_size,
                              hipStream_t stream) {
  const float* x     = (const float*)d_in[0];
  const float* Ww    = (const float*)d_in[1];
  const float* Wb    = (const float*)d_in[2];
  const float* attnw = (const float*)d_in[3];
  const float* iw    = (const float*)d_in[4];
  const float* ib    = (const float*)d_in[5];
  const float* adj   = (const float*)d_in[6];
  float* out = (float*)d_out;

  float* ws = (float*)d_ws;
  float* xp  = ws;                         // 8*13*768 = 79,872
  float* S   = xp + (size_t)Bq * 13 * 768; // 24,576
  float* Wx  = S + (size_t)Bq * HCq * Tq;  // 4,096
  float* WxT = Wx + HCq * F_INq;           // 4,096
  float* Wp  = WxT + F_INq * HCq;          // 256
  float* bx  = Wp + 8 * F_INq;             // 136
  int* nbr_cnt = (int*)(bx + 136);
  int* nbr_idx = nbr_cnt + Nq;
  float* nbr_w = (float*)(nbr_idx + Nq * KMAX);

  prep_kernel<<<Nq + 1 + Bq * 13, 192, 0, stream>>>(
      iw, ib, adj, Ww, Wb, attnw, x,
      nbr_cnt, nbr_idx, nbr_w, Wx, WxT, Wp, bx, xp);
  sgemm_kernel<<<Bq, 192, 0, stream>>>(xp, Wx, bx, S);
  fused_kernel<<<(Bq * Nq) / 2, 256, 0, stream>>>(x, Wp, WxT, bx, S,
                                                  nbr_cnt, nbr_idx, nbr_w, out);
}

// Round 7
// 104.716 us; speedup vs baseline: 2.2471x; 1.0778x over previous
//
#include <hip/hip_runtime.h>
#include <math.h>

#define Bq 8
#define Nq 325
#define F_INq 32
#define Tq 24
#define HCq 128
#define KMAX 4

// ---- K1: blocks 0..324 neighbor extract (wave0, ballot rank); block 325: packs;
//      blocks 326..429: xpart partial sums over 25-node chunks --------------------
__global__ __launch_bounds__(192) void prep_kernel(
    const float* __restrict__ iw, const float* __restrict__ ib,
    const float* __restrict__ adj, const float* __restrict__ Ww,
    const float* __restrict__ Wb, const float* __restrict__ attnw,
    const float* __restrict__ x,
    int* __restrict__ nbr_cnt, int* __restrict__ nbr_idx, float* __restrict__ nbr_w,
    float* __restrict__ WxT, float* __restrict__ Wp,
    float* __restrict__ bx, float* __restrict__ xp) {
  int blk = blockIdx.x;
  int tid = threadIdx.x;
  if (blk < Nq) {
    if (tid >= 64) return;               // wave 0 only; no barriers in this path
    int lane = tid;
    int i = blk;
    const float* iwr = iw + (size_t)i * Nq;
    const float* ibr = ib + (size_t)i * Nq;
    const float* ar  = adj + (size_t)i * Nq;
    float wa_c[6], a_c[6];
    float sum = 0.f;
    #pragma unroll
    for (int c = 0; c < 6; ++c) {
      int j = c * 64 + lane;
      float wa = 0.f, a = 0.f;
      if (j < Nq) {
        float basev = ibr[j];
        float w = iwr[j];
        w = fminf(fmaxf(w, basev * 0.5f), basev * 1.5f);
        w = fmaxf(w, 0.f);
        a = ar[j];
        wa = w * a;
      }
      wa_c[c] = wa; a_c[c] = a;
      sum += wa;
    }
    #pragma unroll
    for (int off = 32; off >= 1; off >>= 1) sum += __shfl_xor(sum, off, 64);
    if (sum == 0.f) sum = 1e-6f;
    float inv = 1.f / sum;
    unsigned long long below = (1ull << lane) - 1ull;
    int base = 0;
    #pragma unroll
    for (int c = 0; c < 6; ++c) {
      int j = c * 64 + lane;
      bool pred = (j < Nq) && (a_c[c] != 0.f);
      unsigned long long m = __ballot(pred);
      int rank = base + __popcll(m & below);
      if (pred && rank < KMAX) {
        nbr_idx[i * KMAX + rank] = j;
        nbr_w[i * KMAX + rank]   = wa_c[c] * inv;
      }
      base += __popcll(m);
    }
    if (lane == 0) {
      int cnt = base < KMAX ? base : KMAX;
      for (int k = cnt; k < KMAX; ++k) { nbr_idx[i * KMAX + k] = 0; nbr_w[i * KMAX + k] = 0.f; }
      nbr_cnt[i] = cnt;
    }
    return;
  }
  if (blk == Nq) {
    // WxT[f][r] = Ww[r][f] for fused GEMM wave-uniform s_loads
    for (int o = tid; o < F_INq * HCq; o += 192) {
      int f = o >> 7, r = o & 127;
      WxT[o] = Ww[r * F_INq + f];
    }
    // Wp[p][f]: p=0..3 a1-projected row per head; p=4..7 a2-projected
    for (int o = tid; o < 8 * F_INq; o += 192) {
      int p = o >> 5, f = o & 31;
      int h = p & 3, c0 = (p < 4) ? 0 : 32;
      float v = 0.f;
      for (int c = 0; c < 32; ++c)
        v += Ww[(h * 32 + c) * F_INq + f] * attnw[h * 64 + c0 + c];
      Wp[o] = v;
    }
    // bx[0..127]=Wb; bx[128+h]=a1-proj bias; bx[132+h]=a2-proj bias
    for (int r = tid; r < 136; r += 192) {
      float v;
      if (r < HCq) {
        v = Wb[r];
      } else {
        int h = (r - HCq) & 3, c0 = (r < 132) ? 0 : 32;
        v = 0.f;
        for (int c = 0; c < 32; ++c) v += Wb[h * 32 + c] * attnw[h * 64 + c0 + c];
      }
      bx[r] = v;
    }
    return;
  }
  // xpart: partial sums of x over 25-node chunks
  {
    int pblk = blk - (Nq + 1);            // 0..103 = b*13 + c
    int b = pblk / 13, c = pblk - b * 13;
    const float4* src = (const float4*)x + ((size_t)b * Nq + c * 25) * 192;
    float4 a = {0.f, 0.f, 0.f, 0.f};
    #pragma unroll 5
    for (int n = 0; n < 25; ++n) {
      float4 v = src[(size_t)n * 192 + tid];
      a.x += v.x; a.y += v.y; a.z += v.z; a.w += v.w;
    }
    ((float4*)xp)[(size_t)pblk * 192 + tid] = a;
  }
}

// ---- K2: fused tables + GEMM with S folded in (bp*xs term) + coalesced store ------
// Block = 2 nodes (i0, i0+1) of one b. Wave w <-> head h=w (rows 32w..32w+31).
__global__ __launch_bounds__(256) void fused_kernel(
    const float* __restrict__ x, const float* __restrict__ Wp,
    const float* __restrict__ WxT, const float* __restrict__ bx,
    const float* __restrict__ xp,
    const int* __restrict__ nbr_cnt, const int* __restrict__ nbr_idx,
    const float* __restrict__ nbr_w, float* __restrict__ out) {
  __shared__ __align__(16) float sx[6144];          // [ii][slot][f*24+t]; reused as out tile
  __shared__ __align__(16) float sxs[768];          // xs[b][f*24+t]
  __shared__ __align__(16) float spd[2][3][96];     // pd_k[ii][k][h*24+t]
  __shared__ float sbp[2][96], sps[2][96];
  __shared__ float ssw[2][3];
  __shared__ int ssi[2][3], scnt2[2];
  int tid = threadIdx.x;
  int blk = blockIdx.x;
  int b = blk / 163;
  int i0 = (blk - b * 163) * 2;
  int valid1 = (i0 + 1 < Nq) ? 1 : 0;
  if (tid < 2) {
    int i = i0 + (tid & valid1);
    int c = nbr_cnt[i];
    scnt2[tid] = c < 3 ? c : 3;
  }
  if (tid < 6) {
    int ii = tid / 3, k = tid - ii * 3;
    int i = i0 + (ii & valid1);
    ssi[ii][k] = nbr_idx[i * KMAX + k];
    ssw[ii][k] = nbr_w[i * KMAX + k];
  }
  __syncthreads();
  // stage x tiles (8 slots, coalesced float4) + xs reduction from 13 partials
  const float4* x4 = (const float4*)x;
  float4* sx4 = (float4*)sx;
  #pragma unroll
  for (int j = 0; j < 6; ++j) {
    int idx = tid + j * 256;              // [0,1536)
    int slot = idx / 192, e4 = idx - slot * 192;
    int ii = slot >> 2, sl = slot & 3;
    int node = (sl == 0) ? (i0 + (ii & valid1)) : ssi[ii][sl - 1];
    sx4[idx] = x4[((size_t)(b * Nq + node)) * 192 + e4];
  }
  if (tid < 192) {
    const float4* xpb = (const float4*)xp + (size_t)b * 13 * 192;
    float4 a = {0.f, 0.f, 0.f, 0.f};
    #pragma unroll
    for (int c = 0; c < 13; ++c) {
      float4 v = xpb[c * 192 + tid];
      a.x += v.x; a.y += v.y; a.z += v.z; a.w += v.w;
    }
    ((float4*)sxs)[tid] = a;
  }
  __syncthreads();
  // tables: f1(self)+f2(nbrs) -> sparse-softmax factors per (ii,h,t)
  if (tid < 192) {
    int ii = tid / 96, r96 = tid - ii * 96;
    int h = r96 / 24, t = r96 - h * 24;
    const float* xi  = sx + (ii * 4 + 0) * 768 + t;
    const float* xj0 = sx + (ii * 4 + 1) * 768 + t;
    const float* xj1 = sx + (ii * 4 + 2) * 768 + t;
    const float* xj2 = sx + (ii * 4 + 3) * 768 + t;
    const float* w1 = Wp + h * 32;
    const float* w2 = Wp + (4 + h) * 32;
    float f1 = bx[128 + h], g0 = bx[132 + h], g1 = g0, g2 = g0;
    #pragma unroll
    for (int f = 0; f < 32; ++f) {
      float wa = w1[f], wb2 = w2[f];
      f1 += wa * xi[f * 24];
      g0 += wb2 * xj0[f * 24];
      g1 += wb2 * xj1[f * 24];
      g2 += wb2 * xj2[f * 24];
    }
    int cnt = scnt2[ii];
    float fv[3] = {g0, g1, g2};
    float sv[3];
    float m = 0.f;                        // >= N-cnt exact-zero score entries
    #pragma unroll
    for (int k = 0; k < 3; ++k) {
      float s = 0.f;
      if (k < cnt) {
        float e = f1 + fv[k];
        e = e > 0.f ? e : 0.2f * e;       // leaky_relu 0.2
        s = e + ssw[ii][k];
        m = fmaxf(m, s);
      }
      sv[k] = s;
    }
    float em = __expf(-m);
    float Z = (float)(Nq - cnt) * em;
    float pk[3];
    #pragma unroll
    for (int k = 0; k < 3; ++k) {
      float p = 0.f;
      if (k < cnt) { p = __expf(sv[k] - m); Z += p; }
      pk[k] = p;
    }
    float invZ = 1.f / Z;
    float bp = em * invZ;
    float ps = 0.f;
    sbp[ii][r96] = bp;
    #pragma unroll
    for (int k = 0; k < 3; ++k) {
      float pd = (k < cnt) ? pk[k] * invZ - bp : 0.f;
      spd[ii][k][r96] = pd;
      ps += pd;
    }
    sps[ii][r96] = ps;
  }
  __syncthreads();
  // GEMM with S folded: yv = p0*x1+p1*x2+p2*x3 + bp*xs; acc init = (ps+325*bp)*bx
  int lane = tid & 63;
  int w = __builtin_amdgcn_readfirstlane(tid >> 6);   // wave id = head (uniform)
  int ii = lane / 24, t = lane - ii * 24;
  bool act = (lane < 48);
  float acc[32];
  if (act) {
    int ht = w * 24 + t;
    float bpv = sbp[ii][ht];
    float psv = sps[ii][ht];
    float p0 = spd[ii][0][ht], p1 = spd[ii][1][ht], p2 = spd[ii][2][ht];
    float initc = psv + 325.f * bpv;
    const float* bxp = bx + w * 32;                   // uniform -> s_load
    #pragma unroll
    for (int r = 0; r < 32; ++r) acc[r] = initc * bxp[r];
    const float* xj0 = sx + (ii * 4 + 1) * 768 + t;
    const float* xj1 = sx + (ii * 4 + 2) * 768 + t;
    const float* xj2 = sx + (ii * 4 + 3) * 768 + t;
    const float* xsp = sxs + t;
    const float* wtp = WxT + w * 32;                  // uniform -> s_load
    #pragma unroll 4
    for (int f = 0; f < 32; ++f) {
      float yv = p0 * xj0[f * 24] + p1 * xj1[f * 24] + p2 * xj2[f * 24]
               + bpv * xsp[f * 24];
      const float* wr = wtp + f * 128;
      #pragma unroll
      for (int r = 0; r < 32; ++r) acc[r] += wr[r] * yv;
    }
  }
  __syncthreads();                        // all reads of sx done before overwrite
  if (act) {
    float* otp = sx + ii * 3072 + (w * 32) * 24 + t;
    #pragma unroll
    for (int r = 0; r < 32; ++r) otp[r * 24] = acc[r];
  }
  __syncthreads();
  // coalesced float4 store (skip second node on the tail block)
  float4* o4 = (float4*)(out + ((size_t)(b * Nq + i0)) * 3072);
  int lim = valid1 ? 1536 : 768;
  #pragma unroll
  for (int j = 0; j < 6; ++j) {
    int idx = tid + j * 256;
    if (idx < lim) o4[idx] = sx4[idx];
  }
}

extern "C" void kernel_launch(void* const* d_in, const int* in_sizes, int n_in,
                              void* d_out, int out_size, void* d_ws, size_t ws_size,
                              hipStream_t stream) {
  const float* x     = (const float*)d_in[0];
  const float* Ww    = (const float*)d_in[1];
  const float* Wb    = (const float*)d_in[2];
  const float* attnw = (const float*)d_in[3];
  const float* iw    = (const float*)d_in[4];
  const float* ib    = (const float*)d_in[5];
  const float* adj   = (const float*)d_in[6];
  float* out = (float*)d_out;

  float* ws = (float*)d_ws;
  float* xp  = ws;                         // 8*13*768 = 79,872
  float* WxT = xp + (size_t)Bq * 13 * 768; // 4,096
  float* Wp  = WxT + F_INq * HCq;          // 256
  float* bx  = Wp + 8 * F_INq;             // 136
  int* nbr_cnt = (int*)(bx + 136);
  int* nbr_idx = nbr_cnt + Nq;
  float* nbr_w = (float*)(nbr_idx + Nq * KMAX);

  prep_kernel<<<Nq + 1 + Bq * 13, 192, 0, stream>>>(
      iw, ib, adj, Ww, Wb, attnw, x,
      nbr_cnt, nbr_idx, nbr_w, WxT, Wp, bx, xp);
  fused_kernel<<<Bq * 163, 256, 0, stream>>>(x, Wp, WxT, bx, xp,
                                             nbr_cnt, nbr_idx, nbr_w, out);
}